// Round 9
// baseline (524.049 us; speedup 1.0000x reference)
//
#include <hip/hip_runtime.h>

typedef float f32x4 __attribute__((ext_vector_type(4)));
typedef short bf16x8 __attribute__((ext_vector_type(8)));

__device__ __forceinline__ unsigned short bf16r(float f) {
  unsigned int u = __float_as_uint(f);
  return (unsigned short)((u + 0x7FFFu + ((u >> 16) & 1u)) >> 16);
}
__device__ __forceinline__ float bf2f(unsigned short h) {
  return __uint_as_float((unsigned int)h << 16);
}

// async global->LDS, 16B per lane; LDS dest = wave-uniform base + lane*16
__device__ __forceinline__ void gload_lds16(const unsigned short* g, unsigned short* l) {
  __builtin_amdgcn_global_load_lds(
      (const __attribute__((address_space(1))) unsigned int*)g,
      (__attribute__((address_space(3))) unsigned int*)l, 16, 0, 0);
}

// ================= CSR build =================
__global__ __launch_bounds__(256) void hist_kernel(const int* __restrict__ dst,
                                                   int* __restrict__ deg, int E) {
  int e = blockIdx.x * 256 + threadIdx.x;
  if (e < E) atomicAdd(&deg[dst[e]], 1);
}

__global__ __launch_bounds__(1024) void scan_kernel(const int* __restrict__ deg,
                                                    int* __restrict__ rowstart,
                                                    int* __restrict__ cursor, int N) {
  __shared__ int sums[1024];
  const int t = threadIdx.x;
  const int CH = (N + 1023) >> 10;
  int local[32];
  int base = t * CH;
  int s = 0;
  for (int i = 0; i < CH; i++) {
    int idx = base + i;
    int v = (idx < N) ? deg[idx] : 0;
    local[i] = s;
    s += v;
  }
  sums[t] = s;
  __syncthreads();
  for (int off = 1; off < 1024; off <<= 1) {
    int add = (t >= off) ? sums[t - off] : 0;
    __syncthreads();
    sums[t] += add;
    __syncthreads();
  }
  int prefix = sums[t] - s;
  for (int i = 0; i < CH; i++) {
    int idx = base + i;
    if (idx < N) {
      int v = prefix + local[i];
      rowstart[idx] = v;
      cursor[idx] = v;
    }
  }
  if (t == 1023) rowstart[N] = sums[1023];
}

__global__ __launch_bounds__(256) void fill_kernel(const int* __restrict__ src,
                                                   const int* __restrict__ dst,
                                                   int* __restrict__ cursor,
                                                   int* __restrict__ nbr, int E) {
  int e = blockIdx.x * 256 + threadIdx.x;
  if (e >= E) return;
  int pos = atomicAdd(&cursor[dst[e]], 1);
  nbr[pos] = src[e];
}

// ============ gather + (optional BN+ReLU on inputs) -> fragment-linear bf16 hi/lo ============
// addr = ((panel*KT + kt)*4 + rt)*512 + (lr | (lc<<4))*8 + jj
template <int C, bool BNIN>
__global__ __launch_bounds__(256) void gather_agg_kernel(
    const float* __restrict__ x, const int* __restrict__ rowstart,
    const int* __restrict__ nbr, const float* __restrict__ stats,
    unsigned short* __restrict__ AH, unsigned short* __restrict__ AL, int N) {
  constexpr int Din = 64 * C;
  constexpr int KT = Din >> 5;
  const int wave = threadIdx.x >> 6;
  const int lane = threadIdx.x & 63;
  const int node = blockIdx.x * 4 + wave;
  if (node >= N) return;

  float sc[C], sh[C];
  if constexpr (BNIN) {
#pragma unroll
    for (int j = 0; j < C; j++) {
      sc[j] = stats[lane * C + j];
      sh[j] = stats[Din + lane * C + j];
    }
  }

  float acc[C];
  {
    const float* p = x + (size_t)node * Din + lane * C;
    float v[C];
    if constexpr (C == 2) {
      float2 t = *(const float2*)p; v[0] = t.x; v[1] = t.y;
    } else {
      float4 t = *(const float4*)p; v[0] = t.x; v[1] = t.y; v[2] = t.z; v[3] = t.w;
    }
#pragma unroll
    for (int j = 0; j < C; j++)
      acc[j] = BNIN ? fmaxf(v[j] * sc[j] + sh[j], 0.f) : v[j];
  }
  const int rs = rowstart[node], re = rowstart[node + 1];
  for (int e = rs; e < re; e++) {
    int s0 = nbr[e];
    const float* p = x + (size_t)s0 * Din + lane * C;
    float v[C];
    if constexpr (C == 2) {
      float2 t = *(const float2*)p; v[0] = t.x; v[1] = t.y;
    } else {
      float4 t = *(const float4*)p; v[0] = t.x; v[1] = t.y; v[2] = t.z; v[3] = t.w;
    }
#pragma unroll
    for (int j = 0; j < C; j++)
      acc[j] += BNIN ? fmaxf(v[j] * sc[j] + sh[j], 0.f) : v[j];
  }

  unsigned short hi[C], lo[C];
#pragma unroll
  for (int j = 0; j < C; j++) {
    hi[j] = bf16r(acc[j]);
    lo[j] = bf16r(acc[j] - bf2f(hi[j]));
  }
  const int panel = node >> 6;
  const int rt = (node >> 4) & 3;
  const int lr = node & 15;
  int kt, lc, jj;
  if constexpr (C == 4) {
    kt = lane >> 3; lc = (lane >> 1) & 3; jj = (lane & 1) * 4;
  } else {
    kt = lane >> 4; lc = (lane >> 2) & 3; jj = (lane & 3) * 2;
  }
  size_t addr = (((size_t)panel * KT + kt) * 4 + rt) * 512 + (size_t)(lr | (lc << 4)) * 8 + jj;
  if constexpr (C == 4) {
    *(ushort4*)(AH + addr) = make_ushort4(hi[0], hi[1], hi[2], hi[3]);
    *(ushort4*)(AL + addr) = make_ushort4(lo[0], lo[1], lo[2], lo[3]);
  } else {
    *(ushort2*)(AH + addr) = make_ushort2(hi[0], hi[1]);
    *(ushort2*)(AL + addr) = make_ushort2(lo[0], lo[1]);
  }
}

// ================= weight prep: W[K][N] fp32 -> WT_hi/lo [N][K] bf16 =================
__global__ __launch_bounds__(256) void wprep_kernel(const float* __restrict__ W,
                                                    unsigned short* __restrict__ TH,
                                                    unsigned short* __restrict__ TL,
                                                    int K, int N) {
  int idx = blockIdx.x * 256 + threadIdx.x;
  if (idx >= K * N) return;
  int k = idx / N, n = idx - k * N;
  float v = W[idx];
  unsigned short h = bf16r(v);
  TH[(size_t)n * K + k] = h;
  TL[(size_t)n * K + k] = bf16r(v - bf2f(h));
}

// ===== MFMA GEMM: 64x64 tile, ONE wave per block, barrier-free pipelined staging =====
// Per iter: [ds_read A(t)] -> [B loads(t)] -> [STAGE(t+1)] -> [MFMA]; sched_barriers pin
// the vmem FIFO order so automatic waitcnts never drain the in-flight prefetch.
// Swapped operands: mfma(b_frag, a_frag) -> row = lane&15, col = (lane>>4)*4 + reg.
template <bool FRAGOUT>
__global__ __launch_bounds__(64, 1) void gemm_mfma_kernel(
    const unsigned short* __restrict__ AH, const unsigned short* __restrict__ AL,
    const unsigned short* __restrict__ BT_hi, const unsigned short* __restrict__ BT_lo,
    const float* __restrict__ bias, float* __restrict__ C,
    unsigned short* __restrict__ OH, unsigned short* __restrict__ OL,
    int M, int K, int N, int mblocks, int cbShift, float* __restrict__ stats) {
  __shared__ unsigned short bufH[2][4096];
  __shared__ unsigned short bufL[2][4096];
  const int bid = blockIdx.x;
  const int xcd = bid & 7;
  const int q = bid >> 3;
  const int r = ((q >> cbShift) << 3) + xcd;
  const int cb = q & ((1 << cbShift) - 1);
  if (r >= mblocks) return;

  const int lane = threadIdx.x;  // single wave
  const int rowBase = r * 64;
  const int colBase = cb * 64;
  const int KT = K >> 5;
  const int NI = KT >> 1;

  f32x4 acc[4][4] = {};  // [row-frag][col-frag]
  const int c0 = colBase + (lane & 15);
  const int kf = (lane >> 4) * 8;
  size_t bRow[4];
#pragma unroll
  for (int cf = 0; cf < 4; cf++) bRow[cf] = (size_t)(c0 + cf * 16) * K;
  const size_t tb = (size_t)r * KT * 2048;
  const unsigned short* sH = AH + tb + lane * 8;
  const unsigned short* sL = AL + tb + lane * 8;

  // prologue: stage tile 0
#pragma unroll
  for (int j = 0; j < 8; j++) {
    gload_lds16(sH + j * 512, bufH[0] + j * 512);
    gload_lds16(sL + j * 512, bufL[0] + j * 512);
  }

  for (int t = 0; t < NI; t++) {
    const int cur = t & 1;
    // 1) ds_read all A fragments of tile t (waits stage(t); nothing else in flight)
    bf16x8 a_h[8], a_l[8];
#pragma unroll
    for (int u = 0; u < 8; u++) {
      a_h[u] = *(const bf16x8*)(bufH[cur] + u * 512 + lane * 8);
      a_l[u] = *(const bf16x8*)(bufL[cur] + u * 512 + lane * 8);
    }
    __builtin_amdgcn_sched_barrier(0);
    // 2) B fragments for both 32-K halves (L2-resident)
    bf16x8 bh[2][4], bl[2][4];
#pragma unroll
    for (int h = 0; h < 2; h++) {
      const int kidx = (2 * t + h) * 32 + kf;
#pragma unroll
      for (int cf = 0; cf < 4; cf++) {
        bh[h][cf] = *(const bf16x8*)(BT_hi + bRow[cf] + kidx);
        bl[h][cf] = *(const bf16x8*)(BT_lo + bRow[cf] + kidx);
      }
    }
    __builtin_amdgcn_sched_barrier(0);
    // 3) prefetch tile t+1 (stays in flight across the MFMAs; never awaited early)
    if (t + 1 < NI) {
      const unsigned short* pH = sH + (size_t)(t + 1) * 4096;
      const unsigned short* pL = sL + (size_t)(t + 1) * 4096;
      unsigned short* dH = bufH[cur ^ 1];
      unsigned short* dL = bufL[cur ^ 1];
#pragma unroll
      for (int j = 0; j < 8; j++) {
        gload_lds16(pH + j * 512, dH + j * 512);
        gload_lds16(pL + j * 512, dL + j * 512);
      }
    }
    __builtin_amdgcn_sched_barrier(0);
    // 4) MFMAs
#pragma unroll
    for (int h = 0; h < 2; h++) {
#pragma unroll
      for (int fi = 0; fi < 4; fi++) {
        bf16x8 ah = a_h[h * 4 + fi];
        bf16x8 al = a_l[h * 4 + fi];
#pragma unroll
        for (int cf = 0; cf < 4; cf++) {
          acc[fi][cf] = __builtin_amdgcn_mfma_f32_16x16x32_bf16(bh[h][cf], ah, acc[fi][cf], 0, 0, 0);
          acc[fi][cf] = __builtin_amdgcn_mfma_f32_16x16x32_bf16(bh[h][cf], al, acc[fi][cf], 0, 0, 0);
          acc[fi][cf] = __builtin_amdgcn_mfma_f32_16x16x32_bf16(bl[h][cf], ah, acc[fi][cf], 0, 0, 0);
        }
      }
    }
  }

  const int cj = (lane >> 4) * 4;
  const int lr = lane & 15;
  float4 b4[4];
#pragma unroll
  for (int cf = 0; cf < 4; cf++) b4[cf] = *(const float4*)(bias + colBase + cf * 16 + cj);

  if constexpr (FRAGOUT) {
    const int KTo = N >> 5;
#pragma unroll
    for (int cf = 0; cf < 4; cf++) {
      const int col0 = colBase + cf * 16 + cj;
      const int kt = col0 >> 5, lc = (col0 >> 3) & 3, jj = col0 & 7;
#pragma unroll
      for (int fi = 0; fi < 4; fi++) {
        ushort4 hv, lv;
#pragma unroll
        for (int j = 0; j < 4; j++) {
          float v = acc[fi][cf][j] + ((const float*)&b4[cf])[j];
          v = fmaxf(v, 0.f);
          unsigned short h = bf16r(v);
          ((unsigned short*)&hv)[j] = h;
          ((unsigned short*)&lv)[j] = bf16r(v - bf2f(h));
        }
        size_t addr = (((size_t)r * KTo + kt) * 4 + fi) * 512 + (size_t)(lr | (lc << 4)) * 8 + jj;
        *(ushort4*)(OH + addr) = hv;
        *(ushort4*)(OL + addr) = lv;
      }
    }
  } else {
    float s1c[4][4] = {}, s2c[4][4] = {};
#pragma unroll
    for (int fi = 0; fi < 4; fi++) {
      int row = rowBase + fi * 16 + lr;
      bool ok = row < M;
#pragma unroll
      for (int cf = 0; cf < 4; cf++) {
        float4 v;
#pragma unroll
        for (int j = 0; j < 4; j++)
          ((float*)&v)[j] = acc[fi][cf][j] + ((const float*)&b4[cf])[j];
        if (ok) {
          *(float4*)(C + (size_t)row * N + colBase + cf * 16 + cj) = v;
#pragma unroll
          for (int j = 0; j < 4; j++) {
            float vv = ((const float*)&v)[j];
            s1c[cf][j] += vv;
            s2c[cf][j] += vv * vv;
          }
        }
      }
    }
    if (stats) {
#pragma unroll
      for (int cf = 0; cf < 4; cf++)
#pragma unroll
        for (int j = 0; j < 4; j++) {
#pragma unroll
          for (int off = 1; off < 16; off <<= 1) {
            s1c[cf][j] += __shfl_xor(s1c[cf][j], off);
            s2c[cf][j] += __shfl_xor(s2c[cf][j], off);
          }
        }
      if (lr == 0) {
#pragma unroll
        for (int cf = 0; cf < 4; cf++)
#pragma unroll
          for (int j = 0; j < 4; j++) {
            int col = colBase + cf * 16 + cj + j;
            atomicAdd(&stats[col], s1c[cf][j]);
            atomicAdd(&stats[N + col], s2c[cf][j]);
          }
      }
    }
  }
}

// ================= BN fold =================
__global__ __launch_bounds__(256) void bn_prep_kernel(float* __restrict__ stats,
                                                      const float* __restrict__ gamma,
                                                      const float* __restrict__ beta,
                                                      int D, float invN) {
  int c = blockIdx.x * 256 + threadIdx.x;
  if (c >= D) return;
  float mean = stats[c] * invN;
  float var = stats[D + c] * invN - mean * mean;
  float sc = rsqrtf(var + 1e-5f) * gamma[c];
  stats[c] = sc;
  stats[D + c] = beta[c] - mean * sc;
}

// ============ fused BN+ReLU+segment-mean pool (layer 3, D=512) ============
__global__ __launch_bounds__(256) void bn_pool_kernel(
    const float* __restrict__ h, const float* __restrict__ stats,
    const int* __restrict__ batch, float* __restrict__ pooled, int N) {
  const int g = blockIdx.x >> 3;
  const int s = blockIdx.x & 7;
  __shared__ int s_lo, s_hi;
  if (threadIdx.x == 0) {
    int lo = 0, hi = N;
    while (lo < hi) { int m = (lo + hi) >> 1; if (batch[m] < g) lo = m + 1; else hi = m; }
    s_lo = lo;
    lo = 0; hi = N;
    while (lo < hi) { int m = (lo + hi) >> 1; if (batch[m] < g + 1) lo = m + 1; else hi = m; }
    s_hi = lo;
  }
  __syncthreads();
  const int lo = s_lo, hi = s_hi, len = hi - lo;
  if (len == 0) return;
  const int per = (len + 7) >> 3;
  const int rs = lo + s * per;
  const int re = min(rs + per, hi);
  if (rs >= re) return;
  const int t = threadIdx.x;
  float2 sc = *(const float2*)(stats + 2 * t);
  float2 sh = *(const float2*)(stats + 512 + 2 * t);
  float ax = 0.f, ay = 0.f;
  for (int r = rs; r < re; r++) {
    float2 v = *(const float2*)(h + (size_t)r * 512 + 2 * t);
    ax += fmaxf(v.x * sc.x + sh.x, 0.f);
    ay += fmaxf(v.y * sc.y + sh.y, 0.f);
  }
  float inv = 1.f / (float)len;
  atomicAdd(&pooled[g * 512 + 2 * t], ax * inv);
  atomicAdd(&pooled[g * 512 + 2 * t + 1], ay * inv);
}

// ================= final projection =================
__global__ __launch_bounds__(64) void out_kernel(const float* __restrict__ pooled,
                                                 const float* __restrict__ wo,
                                                 const float* __restrict__ bo,
                                                 float* __restrict__ out) {
  int g = blockIdx.x, o = threadIdx.x;
  float acc = bo[o];
  for (int c = 0; c < 512; c++) acc += pooled[g * 512 + c] * wo[c * 64 + o];
  out[g * 64 + o] = fmaxf(acc, 0.f);
}

extern "C" void kernel_launch(void* const* d_in, const int* in_sizes, int n_in,
                              void* d_out, int out_size, void* d_ws, size_t ws_size,
                              hipStream_t stream) {
  const float* x0 = (const float*)d_in[0];
  const int* ei = (const int*)d_in[1];
  const int* batch = (const int*)d_in[2];
  const int N = in_sizes[0] / 128;
  const int E = in_sizes[1] / 2;
  const int* src = ei;
  const int* dst = ei + E;
  const float* W[3][6];
  for (int li = 0; li < 3; li++)
    for (int k = 0; k < 6; k++) W[li][k] = (const float*)d_in[3 + li * 6 + k];
  const float* wo = (const float*)d_in[21];
  const float* bo = (const float*)d_in[22];
  float* out = (float*)d_out;

  const int mb = (N + 63) / 64;
  const int N2 = mb * 64;

  // workspace layout
  float* h2 = (float*)d_ws;                  // N*512 f32 (pre-BN activations)
  float* stats = h2 + (size_t)N * 512;       // 1024
  float* pooled = stats + 1024;              // 64*512
  int* deg = (int*)(pooled + 64 * 512);      // N
  int* rowstart = deg + N;                   // N+1
  int* cursor = rowstart + N + 1;            // N
  int* nbr = cursor + N;                     // E
  uintptr_t wp = (uintptr_t)(nbr + E);
  wp = (wp + 15) & ~(uintptr_t)15;
  unsigned short* aggH = (unsigned short*)wp;       // N2*256
  unsigned short* aggL = aggH + (size_t)N2 * 256;   // N2*256
  unsigned short* h1H = aggL + (size_t)N2 * 256;    // N2*512
  unsigned short* h1L = h1H + (size_t)N2 * 512;     // N2*512
  unsigned short* wbuf = h1L + (size_t)N2 * 512;

  const int dins[3] = {128, 128, 256};
  const int douts[3] = {128, 256, 512};

  unsigned short* WT[3][4];
  {
    unsigned short* p = wbuf;
    for (int li = 0; li < 3; li++) {
      size_t s1 = (size_t)dins[li] * douts[li];
      size_t s2 = (size_t)douts[li] * douts[li];
      WT[li][0] = p; p += s1;
      WT[li][1] = p; p += s1;
      WT[li][2] = p; p += s2;
      WT[li][3] = p; p += s2;
    }
  }
  for (int li = 0; li < 3; li++) {
    int e1 = dins[li] * douts[li];
    int e2 = douts[li] * douts[li];
    wprep_kernel<<<(e1 + 255) / 256, 256, 0, stream>>>(W[li][0], WT[li][0], WT[li][1], dins[li], douts[li]);
    wprep_kernel<<<(e2 + 255) / 256, 256, 0, stream>>>(W[li][2], WT[li][2], WT[li][3], douts[li], douts[li]);
  }

  // CSR build
  hipMemsetAsync(deg, 0, (size_t)N * sizeof(int), stream);
  hist_kernel<<<(E + 255) / 256, 256, 0, stream>>>(dst, deg, E);
  scan_kernel<<<1, 1024, 0, stream>>>(deg, rowstart, cursor, N);
  fill_kernel<<<(E + 255) / 256, 256, 0, stream>>>(src, dst, cursor, nbr, E);

  const int mb8 = ((mb + 7) / 8) * 8;
  const int gblocks = (N + 3) / 4;
  for (int li = 0; li < 3; li++) {
    int Din = dins[li], Dout = douts[li];
    if (li == 0)
      gather_agg_kernel<2, false><<<gblocks, 256, 0, stream>>>(x0, rowstart, nbr, nullptr, aggH, aggL, N);
    else if (li == 1)
      gather_agg_kernel<2, true><<<gblocks, 256, 0, stream>>>(h2, rowstart, nbr, stats, aggH, aggL, N);
    else
      gather_agg_kernel<4, true><<<gblocks, 256, 0, stream>>>(h2, rowstart, nbr, stats, aggH, aggL, N);

    int cbShift = (Dout == 128) ? 1 : (Dout == 256) ? 2 : 3;  // 64-col blocks
    int nblocks = mb8 << cbShift;
    gemm_mfma_kernel<true><<<nblocks, 64, 0, stream>>>(
        aggH, aggL, WT[li][0], WT[li][1], W[li][1], nullptr, h1H, h1L,
        N, Din, Dout, mb, cbShift, nullptr);
    hipMemsetAsync(stats, 0, 2 * Dout * sizeof(float), stream);
    gemm_mfma_kernel<false><<<nblocks, 64, 0, stream>>>(
        h1H, h1L, WT[li][2], WT[li][3], W[li][3], h2, nullptr, nullptr,
        N, Dout, Dout, mb, cbShift, stats);
    bn_prep_kernel<<<(Dout + 255) / 256, 256, 0, stream>>>(stats, W[li][4], W[li][5], Dout, 1.0f / N);
    if (li == 2) {
      hipMemsetAsync(pooled, 0, 64 * 512 * sizeof(float), stream);
      bn_pool_kernel<<<64 * 8, 256, 0, stream>>>(h2, stats, batch, pooled, N);
    }
  }
  out_kernel<<<64, 64, 0, stream>>>(pooled, wo, bo, out);
}

// Round 10
// 424.516 us; speedup vs baseline: 1.2345x; 1.2345x over previous
//
#include <hip/hip_runtime.h>

typedef float f32x4 __attribute__((ext_vector_type(4)));
typedef short bf16x8 __attribute__((ext_vector_type(8)));

__device__ __forceinline__ unsigned short bf16r(float f) {
  unsigned int u = __float_as_uint(f);
  return (unsigned short)((u + 0x7FFFu + ((u >> 16) & 1u)) >> 16);
}
__device__ __forceinline__ float bf2f(unsigned short h) {
  return __uint_as_float((unsigned int)h << 16);
}

// ================= CSR build =================
__global__ __launch_bounds__(256) void hist_kernel(const int* __restrict__ dst,
                                                   int* __restrict__ deg, int E) {
  int e = blockIdx.x * 256 + threadIdx.x;
  if (e < E) atomicAdd(&deg[dst[e]], 1);
}

__global__ __launch_bounds__(1024) void scan_kernel(const int* __restrict__ deg,
                                                    int* __restrict__ rowstart,
                                                    int* __restrict__ cursor, int N) {
  __shared__ int sums[1024];
  const int t = threadIdx.x;
  const int CH = (N + 1023) >> 10;
  int local[32];
  int base = t * CH;
  int s = 0;
  for (int i = 0; i < CH; i++) {
    int idx = base + i;
    int v = (idx < N) ? deg[idx] : 0;
    local[i] = s;
    s += v;
  }
  sums[t] = s;
  __syncthreads();
  for (int off = 1; off < 1024; off <<= 1) {
    int add = (t >= off) ? sums[t - off] : 0;
    __syncthreads();
    sums[t] += add;
    __syncthreads();
  }
  int prefix = sums[t] - s;
  for (int i = 0; i < CH; i++) {
    int idx = base + i;
    if (idx < N) {
      int v = prefix + local[i];
      rowstart[idx] = v;
      cursor[idx] = v;
    }
  }
  if (t == 1023) rowstart[N] = sums[1023];
}

__global__ __launch_bounds__(256) void fill_kernel(const int* __restrict__ src,
                                                   const int* __restrict__ dst,
                                                   int* __restrict__ cursor,
                                                   int* __restrict__ nbr, int E) {
  int e = blockIdx.x * 256 + threadIdx.x;
  if (e >= E) return;
  int pos = atomicAdd(&cursor[dst[e]], 1);
  nbr[pos] = src[e];
}

// ============ gather aggregation, optional fused BN(scale/shift)+ReLU on inputs ============
template <int C, bool BNIN>
__global__ __launch_bounds__(256) void gather_agg_kernel(
    const float* __restrict__ x, const int* __restrict__ rowstart,
    const int* __restrict__ nbr, const float* __restrict__ stats,
    float* __restrict__ agg, int N) {
  constexpr int Din = 64 * C;
  const int wave = threadIdx.x >> 6;
  const int lane = threadIdx.x & 63;
  const int node = blockIdx.x * 4 + wave;
  if (node >= N) return;

  float sc[C], sh[C];
  if constexpr (BNIN) {
#pragma unroll
    for (int j = 0; j < C; j++) {
      sc[j] = stats[lane * C + j];
      sh[j] = stats[Din + lane * C + j];
    }
  }

  float acc[C];
  {
    const float* p = x + (size_t)node * Din + lane * C;
    float v[C];
    if constexpr (C == 2) {
      float2 t = *(const float2*)p; v[0] = t.x; v[1] = t.y;
    } else {
      float4 t = *(const float4*)p; v[0] = t.x; v[1] = t.y; v[2] = t.z; v[3] = t.w;
    }
#pragma unroll
    for (int j = 0; j < C; j++)
      acc[j] = BNIN ? fmaxf(v[j] * sc[j] + sh[j], 0.f) : v[j];
  }
  const int rs = rowstart[node], re = rowstart[node + 1];
  for (int e = rs; e < re; e++) {
    int s0 = nbr[e];
    const float* p = x + (size_t)s0 * Din + lane * C;
    float v[C];
    if constexpr (C == 2) {
      float2 t = *(const float2*)p; v[0] = t.x; v[1] = t.y;
    } else {
      float4 t = *(const float4*)p; v[0] = t.x; v[1] = t.y; v[2] = t.z; v[3] = t.w;
    }
#pragma unroll
    for (int j = 0; j < C; j++)
      acc[j] += BNIN ? fmaxf(v[j] * sc[j] + sh[j], 0.f) : v[j];
  }
  float* o = agg + (size_t)node * Din + lane * C;
  if constexpr (C == 2) {
    *(float2*)o = make_float2(acc[0], acc[1]);
  } else {
    *(float4*)o = make_float4(acc[0], acc[1], acc[2], acc[3]);
  }
}

// ================= weight prep: W[K][N] fp32 -> WT_hi/lo [N][K] bf16 =================
__global__ __launch_bounds__(256) void wprep_kernel(const float* __restrict__ W,
                                                    unsigned short* __restrict__ TH,
                                                    unsigned short* __restrict__ TL,
                                                    int K, int N) {
  int idx = blockIdx.x * 256 + threadIdx.x;
  if (idx >= K * N) return;
  int k = idx / N, n = idx - k * N;
  float v = W[idx];
  unsigned short h = bf16r(v);
  TH[(size_t)n * K + k] = h;
  TL[(size_t)n * K + k] = bf16r(v - bf2f(h));
}

// ===== MFMA GEMM: C = A[MxK] @ B[KxN] + bias, split-bf16, inline hi/lo conversion =====
// RT rows x 128 cols per block, 4 waves (wave = 32 cols x RT rows), BK=64.
// XCD swizzle: all col-blocks of a row panel land on one XCD.
template <int RT>
__global__ __launch_bounds__(256) void gemm_mfma_kernel(
    const float* __restrict__ A, const unsigned short* __restrict__ BT_hi,
    const unsigned short* __restrict__ BT_lo, const float* __restrict__ bias,
    float* __restrict__ C, int M, int K, int N, int mblocks, int cbShift,
    int doRelu, float* __restrict__ stats) {
  constexpr int NF = RT / 16;       // row frags per 32-K half
  constexpr int NP = RT / 32;       // staging passes per thread
  __shared__ unsigned short Ah[2 * NF * 512];
  __shared__ unsigned short Al[2 * NF * 512];
  const int bid = blockIdx.x;
  const int xcd = bid & 7;
  const int q = bid >> 3;
  const int r = ((q >> cbShift) << 3) + xcd;
  const int cb = q & ((1 << cbShift) - 1);
  if (r >= mblocks) return;

  const int tid = threadIdx.x;
  const int lane = tid & 63;
  const int w = tid >> 6;
  const int rowBase = r * RT;
  const int colBase = cb * 128 + w * 32;

  f32x4 acc[NF][2] = {};

  const int c0 = colBase + (lane & 15);
  const int kfrag = (lane >> 4) * 8;

  // staging mapping
  int srow, slane, sfrag0, kk0;
  if constexpr (RT == 64) {
    srow = tid >> 2;
    const int schunk = tid & 3;
    slane = (srow & 15) | (schunk << 4);
    sfrag0 = srow >> 4;           // frag = i*NF + sfrag0, kk = schunk*8 + i*32
    kk0 = schunk * 8;
  } else {                        // RT == 32
    srow = tid >> 3;
    const int c8 = tid & 7;
    const int lc = c8 & 3, ks = c8 >> 2;
    slane = (srow & 15) | (lc << 4);
    sfrag0 = ks * NF + (srow >> 4);  // single pass
    kk0 = lc * 8 + ks * 32;
  }
  const size_t arowOff = (size_t)(rowBase + srow) * K;
  const bool srowOk = (rowBase + srow) < M;

  for (int k0 = 0; k0 < K; k0 += 64) {
#pragma unroll
    for (int i = 0; i < NP; i++) {
      int kk = k0 + kk0 + (RT == 64 ? i * 32 : 0);
      float v[8];
      if (srowOk) {
        float4 a = *(const float4*)(A + arowOff + kk);
        float4 b = *(const float4*)(A + arowOff + kk + 4);
        v[0] = a.x; v[1] = a.y; v[2] = a.z; v[3] = a.w;
        v[4] = b.x; v[5] = b.y; v[6] = b.z; v[7] = b.w;
      } else {
#pragma unroll
        for (int j = 0; j < 8; j++) v[j] = 0.f;
      }
      bf16x8 h8, l8;
#pragma unroll
      for (int j = 0; j < 8; j++) {
        unsigned short h = bf16r(v[j]);
        h8[j] = (short)h;
        l8[j] = (short)bf16r(v[j] - bf2f(h));
      }
      int frag = (RT == 64 ? i * NF + sfrag0 : sfrag0);
      *(bf16x8*)(Ah + frag * 512 + slane * 8) = h8;
      *(bf16x8*)(Al + frag * 512 + slane * 8) = l8;
    }
    __syncthreads();
#pragma unroll
    for (int ks = 0; ks < 2; ks++) {
      int kidx = k0 + ks * 32 + kfrag;
      bf16x8 bh0 = *(const bf16x8*)(BT_hi + (size_t)c0 * K + kidx);
      bf16x8 bl0 = *(const bf16x8*)(BT_lo + (size_t)c0 * K + kidx);
      bf16x8 bh1 = *(const bf16x8*)(BT_hi + (size_t)(c0 + 16) * K + kidx);
      bf16x8 bl1 = *(const bf16x8*)(BT_lo + (size_t)(c0 + 16) * K + kidx);
#pragma unroll
      for (int fi = 0; fi < NF; fi++) {
        int frag = ks * NF + fi;
        bf16x8 ah = *(const bf16x8*)(Ah + frag * 512 + lane * 8);
        bf16x8 al = *(const bf16x8*)(Al + frag * 512 + lane * 8);
        acc[fi][0] = __builtin_amdgcn_mfma_f32_16x16x32_bf16(ah, bh0, acc[fi][0], 0, 0, 0);
        acc[fi][0] = __builtin_amdgcn_mfma_f32_16x16x32_bf16(al, bh0, acc[fi][0], 0, 0, 0);
        acc[fi][0] = __builtin_amdgcn_mfma_f32_16x16x32_bf16(ah, bl0, acc[fi][0], 0, 0, 0);
        acc[fi][1] = __builtin_amdgcn_mfma_f32_16x16x32_bf16(ah, bh1, acc[fi][1], 0, 0, 0);
        acc[fi][1] = __builtin_amdgcn_mfma_f32_16x16x32_bf16(al, bh1, acc[fi][1], 0, 0, 0);
        acc[fi][1] = __builtin_amdgcn_mfma_f32_16x16x32_bf16(ah, bl1, acc[fi][1], 0, 0, 0);
      }
    }
    __syncthreads();
  }

  // epilogue
  const float bias0 = bias[c0], bias1 = bias[c0 + 16];
  float s1[2] = {0.f, 0.f}, s2[2] = {0.f, 0.f};
  const int rbase = rowBase + (lane >> 4) * 4;
#pragma unroll
  for (int fi = 0; fi < NF; fi++) {
#pragma unroll
    for (int j = 0; j < 4; j++) {
      int row = rbase + fi * 16 + j;
      float v0 = acc[fi][0][j] + bias0;
      float v1 = acc[fi][1][j] + bias1;
      if (doRelu) { v0 = fmaxf(v0, 0.f); v1 = fmaxf(v1, 0.f); }
      if (row < M) {
        C[(size_t)row * N + c0] = v0;
        C[(size_t)row * N + c0 + 16] = v1;
        s1[0] += v0; s2[0] += v0 * v0;
        s1[1] += v1; s2[1] += v1 * v1;
      }
    }
  }
  if (stats) {
#pragma unroll
    for (int off = 16; off < 64; off <<= 1) {
      s1[0] += __shfl_xor(s1[0], off);
      s2[0] += __shfl_xor(s2[0], off);
      s1[1] += __shfl_xor(s1[1], off);
      s2[1] += __shfl_xor(s2[1], off);
    }
    if (lane < 16) {
      atomicAdd(&stats[c0], s1[0]);
      atomicAdd(&stats[N + c0], s2[0]);
      atomicAdd(&stats[c0 + 16], s1[1]);
      atomicAdd(&stats[N + c0 + 16], s2[1]);
    }
  }
}

// ================= BN fold =================
__global__ __launch_bounds__(256) void bn_prep_kernel(float* __restrict__ stats,
                                                      const float* __restrict__ gamma,
                                                      const float* __restrict__ beta,
                                                      int D, float invN) {
  int c = blockIdx.x * 256 + threadIdx.x;
  if (c >= D) return;
  float mean = stats[c] * invN;
  float var = stats[D + c] * invN - mean * mean;
  float sc = rsqrtf(var + 1e-5f) * gamma[c];
  stats[c] = sc;
  stats[D + c] = beta[c] - mean * sc;
}

// ============ fused BN+ReLU+segment-mean pool (layer 3, D=512) ============
__global__ __launch_bounds__(256) void bn_pool_kernel(
    const float* __restrict__ h, const float* __restrict__ stats,
    const int* __restrict__ batch, float* __restrict__ pooled, int N) {
  const int g = blockIdx.x >> 3;
  const int s = blockIdx.x & 7;
  __shared__ int s_lo, s_hi;
  if (threadIdx.x == 0) {
    int lo = 0, hi = N;
    while (lo < hi) { int m = (lo + hi) >> 1; if (batch[m] < g) lo = m + 1; else hi = m; }
    s_lo = lo;
    lo = 0; hi = N;
    while (lo < hi) { int m = (lo + hi) >> 1; if (batch[m] < g + 1) lo = m + 1; else hi = m; }
    s_hi = lo;
  }
  __syncthreads();
  const int lo = s_lo, hi = s_hi, len = hi - lo;
  if (len == 0) return;
  const int per = (len + 7) >> 3;
  const int rs = lo + s * per;
  const int re = min(rs + per, hi);
  if (rs >= re) return;
  const int t = threadIdx.x;
  float2 sc = *(const float2*)(stats + 2 * t);
  float2 sh = *(const float2*)(stats + 512 + 2 * t);
  float ax = 0.f, ay = 0.f;
  for (int r = rs; r < re; r++) {
    float2 v = *(const float2*)(h + (size_t)r * 512 + 2 * t);
    ax += fmaxf(v.x * sc.x + sh.x, 0.f);
    ay += fmaxf(v.y * sc.y + sh.y, 0.f);
  }
  float inv = 1.f / (float)len;
  atomicAdd(&pooled[g * 512 + 2 * t], ax * inv);
  atomicAdd(&pooled[g * 512 + 2 * t + 1], ay * inv);
}

// ================= final projection =================
__global__ __launch_bounds__(64) void out_kernel(const float* __restrict__ pooled,
                                                 const float* __restrict__ wo,
                                                 const float* __restrict__ bo,
                                                 float* __restrict__ out) {
  int g = blockIdx.x, o = threadIdx.x;
  float acc = bo[o];
  for (int c = 0; c < 512; c++) acc += pooled[g * 512 + c] * wo[c * 64 + o];
  out[g * 64 + o] = fmaxf(acc, 0.f);
}

extern "C" void kernel_launch(void* const* d_in, const int* in_sizes, int n_in,
                              void* d_out, int out_size, void* d_ws, size_t ws_size,
                              hipStream_t stream) {
  const float* x0 = (const float*)d_in[0];
  const int* ei = (const int*)d_in[1];
  const int* batch = (const int*)d_in[2];
  const int N = in_sizes[0] / 128;
  const int E = in_sizes[1] / 2;
  const int* src = ei;
  const int* dst = ei + E;
  const float* W[3][6];
  for (int li = 0; li < 3; li++)
    for (int k = 0; k < 6; k++) W[li][k] = (const float*)d_in[3 + li * 6 + k];
  const float* wo = (const float*)d_in[21];
  const float* bo = (const float*)d_in[22];
  float* out = (float*)d_out;

  // workspace layout
  float* agg = (float*)d_ws;                 // N*256
  float* h1 = agg + (size_t)N * 256;         // N*512
  float* h2 = h1 + (size_t)N * 512;          // N*512
  float* stats = h2 + (size_t)N * 512;       // 1024
  float* pooled = stats + 1024;              // 64*512
  int* deg = (int*)(pooled + 64 * 512);      // N
  int* rowstart = deg + N;                   // N+1
  int* cursor = rowstart + N + 1;            // N
  int* nbr = cursor + N;                     // E
  uintptr_t wp = (uintptr_t)(nbr + E);
  wp = (wp + 15) & ~(uintptr_t)15;
  unsigned short* wbuf = (unsigned short*)wp;

  const int dins[3] = {128, 128, 256};
  const int douts[3] = {128, 256, 512};

  unsigned short* WT[3][4];
  {
    unsigned short* p = wbuf;
    for (int li = 0; li < 3; li++) {
      size_t s1 = (size_t)dins[li] * douts[li];
      size_t s2 = (size_t)douts[li] * douts[li];
      WT[li][0] = p; p += s1;
      WT[li][1] = p; p += s1;
      WT[li][2] = p; p += s2;
      WT[li][3] = p; p += s2;
    }
  }
  for (int li = 0; li < 3; li++) {
    int e1 = dins[li] * douts[li];
    int e2 = douts[li] * douts[li];
    wprep_kernel<<<(e1 + 255) / 256, 256, 0, stream>>>(W[li][0], WT[li][0], WT[li][1], dins[li], douts[li]);
    wprep_kernel<<<(e2 + 255) / 256, 256, 0, stream>>>(W[li][2], WT[li][2], WT[li][3], douts[li], douts[li]);
  }

  // CSR build
  hipMemsetAsync(deg, 0, (size_t)N * sizeof(int), stream);
  hist_kernel<<<(E + 255) / 256, 256, 0, stream>>>(dst, deg, E);
  scan_kernel<<<1, 1024, 0, stream>>>(deg, rowstart, cursor, N);
  fill_kernel<<<(E + 255) / 256, 256, 0, stream>>>(src, dst, cursor, nbr, E);

  const int mb64 = (N + 63) / 64;
  const int mb64_8 = ((mb64 + 7) / 8) * 8;
  const int mb32 = (N + 31) / 32;
  const int mb32_8 = ((mb32 + 7) / 8) * 8;
  const int gblocks = (N + 3) / 4;

  for (int li = 0; li < 3; li++) {
    int Din = dins[li], Dout = douts[li];
    if (li == 0)
      gather_agg_kernel<2, false><<<gblocks, 256, 0, stream>>>(x0, rowstart, nbr, nullptr, agg, N);
    else if (li == 1)
      gather_agg_kernel<2, true><<<gblocks, 256, 0, stream>>>(h2, rowstart, nbr, stats, agg, N);
    else
      gather_agg_kernel<4, true><<<gblocks, 256, 0, stream>>>(h2, rowstart, nbr, stats, agg, N);

    int cbShift = (Dout == 128) ? 0 : (Dout == 256) ? 1 : 2;
    if (Dout == 128) {
      int nblocks = mb32_8 << cbShift;
      gemm_mfma_kernel<32><<<nblocks, 256, 0, stream>>>(agg, WT[li][0], WT[li][1], W[li][1], h1,
                                                        N, Din, Dout, mb32, cbShift, 1, nullptr);
      hipMemsetAsync(stats, 0, 2 * Dout * sizeof(float), stream);
      gemm_mfma_kernel<32><<<nblocks, 256, 0, stream>>>(h1, WT[li][2], WT[li][3], W[li][3], h2,
                                                        N, Dout, Dout, mb32, cbShift, 0, stats);
    } else {
      int nblocks = mb64_8 << cbShift;
      gemm_mfma_kernel<64><<<nblocks, 256, 0, stream>>>(agg, WT[li][0], WT[li][1], W[li][1], h1,
                                                        N, Din, Dout, mb64, cbShift, 1, nullptr);
      hipMemsetAsync(stats, 0, 2 * Dout * sizeof(float), stream);
      gemm_mfma_kernel<64><<<nblocks, 256, 0, stream>>>(h1, WT[li][2], WT[li][3], W[li][3], h2,
                                                        N, Dout, Dout, mb64, cbShift, 0, stats);
    }
    bn_prep_kernel<<<(Dout + 255) / 256, 256, 0, stream>>>(stats, W[li][4], W[li][5], Dout, 1.0f / N);
    if (li == 2) {
      hipMemsetAsync(pooled, 0, 64 * 512 * sizeof(float), stream);
      bn_pool_kernel<<<64 * 8, 256, 0, stream>>>(h2, stats, batch, pooled, N);
    }
  }
  out_kernel<<<64, 64, 0, stream>>>(pooled, wo, bo, out);
}